// Round 15
// baseline (246.390 us; speedup 1.0000x reference)
//
#include <hip/hip_runtime.h>

#define N_NODES 50000
#define N_EDGES 800000
#define SCAN_TILE 2048  // 256 threads x 8 elems
#define CNT_STRIDE 16   // one counter per 64B line (kills false sharing)
#define GEMM1_BLOCKS 768   // layer-1 gemm portion (256-thread blocks, 3/CU)
#define FUSED_BLOCKS 768   // fused agg+gemm: 512-thr blocks, 3/CU (LDS 52.2KB x3 fits 160KB)
#define HIST_BLOCKS ((N_EDGES + 255) / 256)  // 3125

static_assert(N_NODES < 65536, "col must fit in 16 bits for packed CSR");

typedef __attribute__((ext_vector_type(4))) float f32x4;
typedef __attribute__((ext_vector_type(8))) short bf16x8;

__device__ inline unsigned short f32_to_bf16(float f) {
    unsigned int u = __builtin_bit_cast(unsigned int, f);
    u += 0x7FFF + ((u >> 16) & 1);  // RNE
    return (unsigned short)(u >> 16);
}
__device__ inline float bf16_to_f32(unsigned short h) {
    unsigned int u = ((unsigned int)h) << 16;
    return __builtin_bit_cast(float, u);
}

// ---------------------------------------------------------------------------
// prep: zero cnt (int4-wise; cnt[1] doubles as scan done-flag) + W transposes.
// ---------------------------------------------------------------------------
#define W128  (128 * 128)
#define W64   (128 * 64)
#define CNT4  (N_NODES * CNT_STRIDE / 4)

__global__ void prep(int* __restrict__ cnt, const float* __restrict__ W1,
                     const float* __restrict__ W2, const float* __restrict__ W3,
                     unsigned short* __restrict__ Wt1,
                     unsigned short* __restrict__ Wt2,
                     unsigned short* __restrict__ Wt3) {
    long long r = (long long)blockIdx.x * blockDim.x + threadIdx.x;
    if (r < CNT4) {
        int4 z = {0, 0, 0, 0};
        reinterpret_cast<int4*>(cnt)[r] = z;
        return;
    }
    r -= CNT4;
    if (r < W128) {
        int k = (int)r / 128, m = (int)r % 128;
        Wt1[m * 128 + k] = f32_to_bf16(W1[r]);
        return;
    }
    r -= W128;
    if (r < W128) {
        int k = (int)r / 128, m = (int)r % 128;
        Wt2[m * 128 + k] = f32_to_bf16(W2[r]);
        return;
    }
    r -= W128;
    if (r < W64) {
        int k = (int)r / 64, m = (int)r % 64;
        Wt3[m * 128 + k] = f32_to_bf16(W3[r]);
    }
}

// ---------------------------------------------------------------------------
// MFMA phase, 256-thread variant (4 waves; wave w: rows w*16..+16, all tiles).
// Fragment layouts [measured m89/m91/m120].
// ---------------------------------------------------------------------------
template <int NOUT>
__device__ __forceinline__ void mfma_phase(const unsigned short* Xs,
                                           const unsigned short* Ws,
                                           unsigned short* __restrict__ Yb,
                                           int block_row, int N) {
    constexpr int KP = 128 + 8;
    constexpr int NT = NOUT / 16;
    const int tid = threadIdx.x;
    const int wave = tid >> 6;
    const int lane = tid & 63;
    const int m = lane & 15;
    const int quad = lane >> 4;
    const int rowbase = wave * 16;

    f32x4 acc[NT];
#pragma unroll
    for (int t = 0; t < NT; ++t) acc[t] = (f32x4){0.f, 0.f, 0.f, 0.f};

#pragma unroll
    for (int kt = 0; kt < 4; ++kt) {
        bf16x8 a = *reinterpret_cast<const bf16x8*>(
            Xs + (rowbase + m) * KP + kt * 32 + quad * 8);
#pragma unroll
        for (int t = 0; t < NT; ++t) {
            bf16x8 b = *reinterpret_cast<const bf16x8*>(
                Ws + (t * 16 + m) * KP + kt * 32 + quad * 8);
            acc[t] = __builtin_amdgcn_mfma_f32_16x16x32_bf16(a, b, acc[t], 0, 0, 0);
        }
    }

#pragma unroll
    for (int t = 0; t < NT; ++t) {
#pragma unroll
        for (int r = 0; r < 4; ++r) {
            int grow = block_row + rowbase + quad * 4 + r;
            if (grow < N)
                Yb[(size_t)grow * NOUT + t * 16 + m] = f32_to_bf16(acc[t][r]);
        }
    }
}

// ---------------------------------------------------------------------------
// Mega-dispatch: layer-1 GEMM (fp32 x, on-the-fly bf16 convert) overlapped
// with the rank-histogram (independent work; hist backfills CU slots).
// ---------------------------------------------------------------------------
__global__ __launch_bounds__(256) void gemm1_hist(
    const float* __restrict__ x, const unsigned short* __restrict__ Wt,
    unsigned short* __restrict__ Yb, int N, int ntiles,
    const int* __restrict__ erow, int* __restrict__ cnt, int* __restrict__ rank) {
    constexpr int KP = 128 + 8;
    __shared__ unsigned short Xs[64 * KP];
    __shared__ unsigned short Ws[128 * KP];
    const int tid = threadIdx.x;

    if (blockIdx.x >= GEMM1_BLOCKS) {
        int e = (blockIdx.x - GEMM1_BLOCKS) * blockDim.x + tid;
        if (e < N_EDGES) rank[e] = atomicAdd(&cnt[(size_t)erow[e] * CNT_STRIDE], 1);
        return;
    }

    for (int idx = tid; idx < 128 * 16; idx += 256) {
        int r = idx >> 4, ch = idx & 15;
        uint4 v = *reinterpret_cast<const uint4*>(Wt + r * 128 + ch * 8);
        *reinterpret_cast<uint4*>(Ws + r * KP + ch * 8) = v;
    }

    for (int tile = blockIdx.x; tile < ntiles; tile += GEMM1_BLOCKS) {
        const int block_row = tile * 64;
        for (int idx = tid; idx < 64 * 16; idx += 256) {
            int r = idx >> 4, ch = idx & 15;
            int gr = block_row + r;
            if (gr >= N) gr = N - 1;
            const float4* xp =
                reinterpret_cast<const float4*>(x + (size_t)gr * 128 + ch * 8);
            float4 a = xp[0], b = xp[1];
            uint4 o;
            o.x = (unsigned int)f32_to_bf16(a.x) | ((unsigned int)f32_to_bf16(a.y) << 16);
            o.y = (unsigned int)f32_to_bf16(a.z) | ((unsigned int)f32_to_bf16(a.w) << 16);
            o.z = (unsigned int)f32_to_bf16(b.x) | ((unsigned int)f32_to_bf16(b.y) << 16);
            o.w = (unsigned int)f32_to_bf16(b.z) | ((unsigned int)f32_to_bf16(b.w) << 16);
            *reinterpret_cast<uint4*>(Xs + r * KP + ch * 8) = o;
        }
        __syncthreads();
        mfma_phase<128>(Xs, Ws, Yb, block_row, N);
        __syncthreads();
    }
}

// ---------------------------------------------------------------------------
// Single-dispatch scan (spin on tile-done counter; 25 blocks co-resident).
// ---------------------------------------------------------------------------
__global__ void scan_fused(const int* __restrict__ cnt, int* __restrict__ tsum,
                           int* __restrict__ done, int* __restrict__ rptr,
                           int n, int ntiles) {
    __shared__ int sums[256];
    __shared__ int off_s;
    const int t = threadIdx.x;
    const int b = blockIdx.x;
    const int base = b * SCAN_TILE + t * 8;
    int v[8], pref[8];
    int s = 0;
#pragma unroll
    for (int i = 0; i < 8; ++i) {
        v[i] = (base + i < n) ? cnt[(size_t)(base + i) * CNT_STRIDE] : 0;
        s += v[i];
    }
    sums[t] = s;
    __syncthreads();
    for (int off = 1; off < 256; off <<= 1) {
        int x = (t >= off) ? sums[t - off] : 0;
        __syncthreads();
        sums[t] += x;
        __syncthreads();
    }
    int run = sums[t] - s;
#pragma unroll
    for (int i = 0; i < 8; ++i) {
        pref[i] = run;
        run += v[i];
    }
    if (t == 255) {
        tsum[b] = run;
        __threadfence();
        atomicAdd(done, 1);
    }
    if (t == 0) {
        while (__hip_atomic_load(done, __ATOMIC_ACQUIRE, __HIP_MEMORY_SCOPE_AGENT) <
               ntiles) {
        }
        __threadfence();
        int off = 0;
        for (int i = 0; i < b; ++i) off += tsum[i];
        off_s = off;
        if (b == 0) {
            int tot = 0;
            for (int i = 0; i < ntiles; ++i) tot += tsum[i];
            rptr[n] = tot;
        }
    }
    __syncthreads();
    const int off = off_s;
#pragma unroll
    for (int i = 0; i < 8; ++i) {
        int idx = base + i;
        if (idx < n) rptr[idx] = pref[i] + off;
    }
}

// ---------------------------------------------------------------------------
// Atomic-free CSR fill: slot = rptr[row] + rank[e]; one 4B packed store.
// ---------------------------------------------------------------------------
__global__ void fill_csr(const int* __restrict__ erow, const int* __restrict__ ecol,
                         const float* __restrict__ eval, const int* __restrict__ rptr,
                         const int* __restrict__ rank,
                         unsigned int* __restrict__ cpack) {
    int e = blockIdx.x * blockDim.x + threadIdx.x;
    if (e >= N_EDGES) return;
    int slot = rptr[erow[e]] + rank[e];
    unsigned int p = (unsigned int)(ecol[e] & 0xFFFF) |
                     ((unsigned int)f32_to_bf16(eval[e]) << 16);
    cpack[slot] = p;
}

// ---------------------------------------------------------------------------
// MFMA phase, 512-thread variant (8 waves; wave w: rows (w&3)*16..+16,
// tile-columns (w>>2)*NT/2..+NT/2).
// ---------------------------------------------------------------------------
template <int NOUT>
__device__ __forceinline__ void mfma_phase512(const unsigned short* Xs,
                                              const unsigned short* Ws,
                                              unsigned short* __restrict__ Yb,
                                              int block_row, int N) {
    constexpr int KP = 128 + 8;
    constexpr int NT = NOUT / 16;
    constexpr int NTH = NT / 2;
    const int tid = threadIdx.x;
    const int wave = tid >> 6;
    const int lane = tid & 63;
    const int m = lane & 15;
    const int quad = lane >> 4;
    const int rowbase = (wave & 3) * 16;
    const int tbase = (wave >> 2) * NTH;

    f32x4 acc[NTH];
#pragma unroll
    for (int t = 0; t < NTH; ++t) acc[t] = (f32x4){0.f, 0.f, 0.f, 0.f};

#pragma unroll
    for (int kt = 0; kt < 4; ++kt) {
        bf16x8 a = *reinterpret_cast<const bf16x8*>(
            Xs + (rowbase + m) * KP + kt * 32 + quad * 8);
#pragma unroll
        for (int t = 0; t < NTH; ++t) {
            bf16x8 b = *reinterpret_cast<const bf16x8*>(
                Ws + ((tbase + t) * 16 + m) * KP + kt * 32 + quad * 8);
            acc[t] = __builtin_amdgcn_mfma_f32_16x16x32_bf16(a, b, acc[t], 0, 0, 0);
        }
    }

#pragma unroll
    for (int t = 0; t < NTH; ++t) {
#pragma unroll
        for (int r = 0; r < 4; ++r) {
            int grow = block_row + rowbase + quad * 4 + r;
            if (grow < N)
                Yb[(size_t)grow * NOUT + (tbase + t) * 16 + m] = f32_to_bf16(acc[t][r]);
        }
    }
}

// ---------------------------------------------------------------------------
// Fused aggregation + GEMM (layers 2,3), 512-thread blocks, 3 blocks/CU
// (24 waves/CU; VGPR<=85 via launch_bounds(512,6); LDS 3x52.2KB fits 160KB):
// Phase A: 32 groups x 16 lanes gather-aggregate 64 rows (2 rows/group,
// tiered unroll 8/4/2/1), +bias, ReLU, pack bf16 into LDS Xs.
// Phase B: mfma_phase512.
// ---------------------------------------------------------------------------
template <int NOUT>
__global__ __launch_bounds__(512, 6) void gemm_fused_agg(
    const unsigned short* __restrict__ S,
    const int* __restrict__ rptr, const unsigned int* __restrict__ cpack,
    const float* __restrict__ bias,
    const unsigned short* __restrict__ Wt,
    unsigned short* __restrict__ Yb,
    int N, int ntiles) {
    constexpr int KP = 128 + 8;
    __shared__ unsigned short Xs[64 * KP];
    __shared__ unsigned short Ws[NOUT * KP];
    const int tid = threadIdx.x;
    const int group = tid >> 4;   // 0..31
    const int f8 = tid & 15;

    for (int idx = tid; idx < NOUT * 16; idx += 512) {
        int r = idx >> 4, ch = idx & 15;
        uint4 v = *reinterpret_cast<const uint4*>(Wt + r * 128 + ch * 8);
        *reinterpret_cast<uint4*>(Ws + r * KP + ch * 8) = v;
    }

    float bv[8];
#pragma unroll
    for (int i = 0; i < 8; ++i) bv[i] = bias[f8 * 8 + i];

    for (int tile = blockIdx.x; tile < ntiles; tile += gridDim.x) {
        const int block_row = tile * 64;
#pragma unroll
        for (int r4 = 0; r4 < 2; ++r4) {
            const int row = r4 * 32 + group;
            const int node = block_row + row;
            float acc[8];
#pragma unroll
            for (int i = 0; i < 8; ++i) acc[i] = bv[i];
            if (node < N) {
                const int beg = rptr[node];
                const int end = rptr[node + 1];
                int j = beg;
                for (; j + 8 <= end; j += 8) {
                    unsigned int p[8];
                    uint4 s[8];
#pragma unroll
                    for (int u = 0; u < 8; ++u) p[u] = cpack[j + u];
#pragma unroll
                    for (int u = 0; u < 8; ++u)
                        s[u] = *reinterpret_cast<const uint4*>(
                            S + (size_t)(p[u] & 0xFFFF) * 128 + f8 * 8);
#pragma unroll
                    for (int u = 0; u < 8; ++u) {
                        const float v = bf16_to_f32((unsigned short)(p[u] >> 16));
                        const unsigned short* sp =
                            reinterpret_cast<const unsigned short*>(&s[u]);
#pragma unroll
                        for (int i = 0; i < 8; ++i)
                            acc[i] = fmaf(v, bf16_to_f32(sp[i]), acc[i]);
                    }
                }
                if (j + 4 <= end) {
                    unsigned int p[4];
                    uint4 s[4];
#pragma unroll
                    for (int u = 0; u < 4; ++u) p[u] = cpack[j + u];
#pragma unroll
                    for (int u = 0; u < 4; ++u)
                        s[u] = *reinterpret_cast<const uint4*>(
                            S + (size_t)(p[u] & 0xFFFF) * 128 + f8 * 8);
#pragma unroll
                    for (int u = 0; u < 4; ++u) {
                        const float v = bf16_to_f32((unsigned short)(p[u] >> 16));
                        const unsigned short* sp =
                            reinterpret_cast<const unsigned short*>(&s[u]);
#pragma unroll
                        for (int i = 0; i < 8; ++i)
                            acc[i] = fmaf(v, bf16_to_f32(sp[i]), acc[i]);
                    }
                    j += 4;
                }
                if (j + 2 <= end) {
                    unsigned int p[2];
                    uint4 s[2];
#pragma unroll
                    for (int u = 0; u < 2; ++u) p[u] = cpack[j + u];
#pragma unroll
                    for (int u = 0; u < 2; ++u)
                        s[u] = *reinterpret_cast<const uint4*>(
                            S + (size_t)(p[u] & 0xFFFF) * 128 + f8 * 8);
#pragma unroll
                    for (int u = 0; u < 2; ++u) {
                        const float v = bf16_to_f32((unsigned short)(p[u] >> 16));
                        const unsigned short* sp =
                            reinterpret_cast<const unsigned short*>(&s[u]);
#pragma unroll
                        for (int i = 0; i < 8; ++i)
                            acc[i] = fmaf(v, bf16_to_f32(sp[i]), acc[i]);
                    }
                    j += 2;
                }
                if (j < end) {
                    unsigned int p = cpack[j];
                    uint4 s = *reinterpret_cast<const uint4*>(
                        S + (size_t)(p & 0xFFFF) * 128 + f8 * 8);
                    const float v = bf16_to_f32((unsigned short)(p >> 16));
                    const unsigned short* sp =
                        reinterpret_cast<const unsigned short*>(&s);
#pragma unroll
                    for (int i = 0; i < 8; ++i)
                        acc[i] = fmaf(v, bf16_to_f32(sp[i]), acc[i]);
                }
            }
            uint4 o;
            o.x = (unsigned int)f32_to_bf16(fmaxf(acc[0], 0.f)) |
                  ((unsigned int)f32_to_bf16(fmaxf(acc[1], 0.f)) << 16);
            o.y = (unsigned int)f32_to_bf16(fmaxf(acc[2], 0.f)) |
                  ((unsigned int)f32_to_bf16(fmaxf(acc[3], 0.f)) << 16);
            o.z = (unsigned int)f32_to_bf16(fmaxf(acc[4], 0.f)) |
                  ((unsigned int)f32_to_bf16(fmaxf(acc[5], 0.f)) << 16);
            o.w = (unsigned int)f32_to_bf16(fmaxf(acc[6], 0.f)) |
                  ((unsigned int)f32_to_bf16(fmaxf(acc[7], 0.f)) << 16);
            *reinterpret_cast<uint4*>(Xs + row * KP + f8 * 8) = o;
        }
        __syncthreads();
        mfma_phase512<NOUT>(Xs, Ws, Yb, block_row, N);
        __syncthreads();
    }
}

// ---------------------------------------------------------------------------
// Final aggregation: bf16 source [N,64], + bias, no activation, fp32 out.
// 16 lanes/node, 4 features/lane (uint2). Tiered unroll 8/4/2/1.
// ---------------------------------------------------------------------------
__global__ void aggregate_bf16_64(const unsigned short* __restrict__ S,
                                  const int* __restrict__ rptr,
                                  const unsigned int* __restrict__ cpack,
                                  const float* __restrict__ bias,
                                  float* __restrict__ out, int N) {
    const int node = blockIdx.x * (blockDim.x / 16) + threadIdx.x / 16;
    const int f4 = threadIdx.x & 15;
    if (node >= N) return;
    const int beg = rptr[node];
    const int end = rptr[node + 1];
    float acc[4];
#pragma unroll
    for (int i = 0; i < 4; ++i) acc[i] = bias[f4 * 4 + i];
    int j = beg;
    for (; j + 8 <= end; j += 8) {
        unsigned int p[8];
        uint2 s[8];
#pragma unroll
        for (int u = 0; u < 8; ++u) p[u] = cpack[j + u];
#pragma unroll
        for (int u = 0; u < 8; ++u)
            s[u] = *reinterpret_cast<const uint2*>(S + (size_t)(p[u] & 0xFFFF) * 64 + f4 * 4);
#pragma unroll
        for (int u = 0; u < 8; ++u) {
            const float v = bf16_to_f32((unsigned short)(p[u] >> 16));
            const unsigned short* sp = reinterpret_cast<const unsigned short*>(&s[u]);
#pragma unroll
            for (int i = 0; i < 4; ++i) acc[i] = fmaf(v, bf16_to_f32(sp[i]), acc[i]);
        }
    }
    if (j + 4 <= end) {
        unsigned int p[4];
        uint2 s[4];
#pragma unroll
        for (int u = 0; u < 4; ++u) p[u] = cpack[j + u];
#pragma unroll
        for (int u = 0; u < 4; ++u)
            s[u] = *reinterpret_cast<const uint2*>(S + (size_t)(p[u] & 0xFFFF) * 64 + f4 * 4);
#pragma unroll
        for (int u = 0; u < 4; ++u) {
            const float v = bf16_to_f32((unsigned short)(p[u] >> 16));
            const unsigned short* sp = reinterpret_cast<const unsigned short*>(&s[u]);
#pragma unroll
            for (int i = 0; i < 4; ++i) acc[i] = fmaf(v, bf16_to_f32(sp[i]), acc[i]);
        }
        j += 4;
    }
    if (j + 2 <= end) {
        unsigned int p[2];
        uint2 s[2];
#pragma unroll
        for (int u = 0; u < 2; ++u) p[u] = cpack[j + u];
#pragma unroll
        for (int u = 0; u < 2; ++u)
            s[u] = *reinterpret_cast<const uint2*>(S + (size_t)(p[u] & 0xFFFF) * 64 + f4 * 4);
#pragma unroll
        for (int u = 0; u < 2; ++u) {
            const float v = bf16_to_f32((unsigned short)(p[u] >> 16));
            const unsigned short* sp = reinterpret_cast<const unsigned short*>(&s[u]);
#pragma unroll
            for (int i = 0; i < 4; ++i) acc[i] = fmaf(v, bf16_to_f32(sp[i]), acc[i]);
        }
        j += 2;
    }
    if (j < end) {
        unsigned int p = cpack[j];
        uint2 s = *reinterpret_cast<const uint2*>(S + (size_t)(p & 0xFFFF) * 64 + f4 * 4);
        const float v = bf16_to_f32((unsigned short)(p >> 16));
        const unsigned short* sp = reinterpret_cast<const unsigned short*>(&s);
#pragma unroll
        for (int i = 0; i < 4; ++i) acc[i] = fmaf(v, bf16_to_f32(sp[i]), acc[i]);
    }
    float4 o = {acc[0], acc[1], acc[2], acc[3]};
    *reinterpret_cast<float4*>(out + (size_t)node * 64 + f4 * 4) = o;
}

extern "C" void kernel_launch(void* const* d_in, const int* in_sizes, int n_in,
                              void* d_out, int out_size, void* d_ws, size_t ws_size,
                              hipStream_t stream) {
    const float* x    = (const float*)d_in[0];
    const int*   erow = (const int*)d_in[1];
    const int*   ecol = (const int*)d_in[2];
    const float* eval = (const float*)d_in[3];
    const float* W1   = (const float*)d_in[4];
    const float* b1   = (const float*)d_in[5];
    const float* W2   = (const float*)d_in[6];
    const float* b2   = (const float*)d_in[7];
    const float* W3   = (const float*)d_in[8];
    const float* b3   = (const float*)d_in[9];
    float* out = (float*)d_out;

    const size_t nf = (size_t)N_NODES * 128;
    unsigned short* SA  = (unsigned short*)d_ws;     // support A (A1, then A3)
    unsigned short* SB  = SA + nf;                   // support B (A2)
    unsigned short* Wt1 = SB + nf;
    unsigned short* Wt2 = Wt1 + 128 * 128;
    unsigned short* Wt3 = Wt2 + 128 * 128;
    int*   cnt    = (int*)(Wt3 + 64 * 128);              // N_NODES * CNT_STRIDE
    int*   rank   = cnt + (size_t)N_NODES * CNT_STRIDE;  // N_EDGES
    int*   rptr   = rank + N_EDGES;                      // N_NODES + 1
    unsigned int* cpack = (unsigned int*)(rptr + N_NODES + 1);  // N_EDGES
    int*   stsum  = (int*)(cpack + N_EDGES);             // tiles
    int*   done   = cnt + 1;  // unused cnt slot

    const int blk = 256;
    const int ntiles_g = (N_NODES + 63) / 64;
    const int agg_grid = (int)(((long long)N_NODES * 16 + blk - 1) / blk);
    const int ntiles = (N_NODES + SCAN_TILE - 1) / SCAN_TILE;

    // ---- 1. prep: zero cnt + W transposes (one dispatch)
    {
        long long total = (long long)CNT4 + W128 + W128 + W64;
        prep<<<(int)((total + blk - 1) / blk), blk, 0, stream>>>(
            cnt, W1, W2, W3, Wt1, Wt2, Wt3);
    }

    // ---- 2. layer-1 GEMM overlapped with rank-histogram
    gemm1_hist<<<GEMM1_BLOCKS + HIST_BLOCKS, 256, 0, stream>>>(
        x, Wt1, SA, N_NODES, ntiles_g, erow, cnt, rank);

    // ---- 3. scan -> rptr
    scan_fused<<<ntiles, 256, 0, stream>>>(cnt, stsum, done, rptr, N_NODES, ntiles);

    // ---- 4. atomic-free CSR fill
    fill_csr<<<HIST_BLOCKS, blk, 0, stream>>>(erow, ecol, eval, rptr, rank, cpack);

    // ---- 5. Layer 2: fused agg(A1)+ReLU+b1 -> GEMM W2 -> A2
    gemm_fused_agg<128><<<FUSED_BLOCKS, 512, 0, stream>>>(
        SA, rptr, cpack, b1, Wt2, SB, N_NODES, ntiles_g);

    // ---- 6. Layer 3: fused agg(A2)+ReLU+b2 -> GEMM W3 -> A3 (64-wide)
    gemm_fused_agg<64><<<FUSED_BLOCKS, 512, 0, stream>>>(
        SB, rptr, cpack, b2, Wt3, SA, N_NODES, ntiles_g);

    // ---- 7. Final aggregation: A3 + b3 -> out (fp32)
    aggregate_bf16_64<<<agg_grid, blk, 0, stream>>>(SA, rptr, cpack, b3, out, N_NODES);
}

// Round 16
// 232.707 us; speedup vs baseline: 1.0588x; 1.0588x over previous
//
#include <hip/hip_runtime.h>

#define N_NODES 50000
#define N_EDGES 800000
#define SCAN_TILE 2048  // 256 threads x 8 elems
#define CNT_STRIDE 16   // one counter per 64B line (kills false sharing)
#define GEMM1_BLOCKS 768   // layer-1 gemm portion (256-thread blocks, 3/CU)
#define FUSED_BLOCKS 512   // fused agg+gemm: 512-thr blocks, 2/CU (empirical best)
#define HIST_BLOCKS ((N_EDGES + 255) / 256)  // 3125

static_assert(N_NODES < 65536, "col must fit in 16 bits for packed CSR");

typedef __attribute__((ext_vector_type(4))) float f32x4;
typedef __attribute__((ext_vector_type(8))) short bf16x8;

__device__ inline unsigned short f32_to_bf16(float f) {
    unsigned int u = __builtin_bit_cast(unsigned int, f);
    u += 0x7FFF + ((u >> 16) & 1);  // RNE
    return (unsigned short)(u >> 16);
}
__device__ inline float bf16_to_f32(unsigned short h) {
    unsigned int u = ((unsigned int)h) << 16;
    return __builtin_bit_cast(float, u);
}

// ---------------------------------------------------------------------------
// prep: zero cnt (int4-wise; cnt[1] doubles as scan done-flag) + W transposes.
// ---------------------------------------------------------------------------
#define W128  (128 * 128)
#define W64   (128 * 64)
#define CNT4  (N_NODES * CNT_STRIDE / 4)

__global__ void prep(int* __restrict__ cnt, const float* __restrict__ W1,
                     const float* __restrict__ W2, const float* __restrict__ W3,
                     unsigned short* __restrict__ Wt1,
                     unsigned short* __restrict__ Wt2,
                     unsigned short* __restrict__ Wt3) {
    long long r = (long long)blockIdx.x * blockDim.x + threadIdx.x;
    if (r < CNT4) {
        int4 z = {0, 0, 0, 0};
        reinterpret_cast<int4*>(cnt)[r] = z;
        return;
    }
    r -= CNT4;
    if (r < W128) {
        int k = (int)r / 128, m = (int)r % 128;
        Wt1[m * 128 + k] = f32_to_bf16(W1[r]);
        return;
    }
    r -= W128;
    if (r < W128) {
        int k = (int)r / 128, m = (int)r % 128;
        Wt2[m * 128 + k] = f32_to_bf16(W2[r]);
        return;
    }
    r -= W128;
    if (r < W64) {
        int k = (int)r / 64, m = (int)r % 64;
        Wt3[m * 128 + k] = f32_to_bf16(W3[r]);
    }
}

// ---------------------------------------------------------------------------
// MFMA phase, 256-thread variant (4 waves; wave w: rows w*16..+16, all tiles).
// Fragment layouts [measured m89/m91/m120].
// ---------------------------------------------------------------------------
template <int NOUT>
__device__ __forceinline__ void mfma_phase(const unsigned short* Xs,
                                           const unsigned short* Ws,
                                           unsigned short* __restrict__ Yb,
                                           int block_row, int N) {
    constexpr int KP = 128 + 8;
    constexpr int NT = NOUT / 16;
    const int tid = threadIdx.x;
    const int wave = tid >> 6;
    const int lane = tid & 63;
    const int m = lane & 15;
    const int quad = lane >> 4;
    const int rowbase = wave * 16;

    f32x4 acc[NT];
#pragma unroll
    for (int t = 0; t < NT; ++t) acc[t] = (f32x4){0.f, 0.f, 0.f, 0.f};

#pragma unroll
    for (int kt = 0; kt < 4; ++kt) {
        bf16x8 a = *reinterpret_cast<const bf16x8*>(
            Xs + (rowbase + m) * KP + kt * 32 + quad * 8);
#pragma unroll
        for (int t = 0; t < NT; ++t) {
            bf16x8 b = *reinterpret_cast<const bf16x8*>(
                Ws + (t * 16 + m) * KP + kt * 32 + quad * 8);
            acc[t] = __builtin_amdgcn_mfma_f32_16x16x32_bf16(a, b, acc[t], 0, 0, 0);
        }
    }

#pragma unroll
    for (int t = 0; t < NT; ++t) {
#pragma unroll
        for (int r = 0; r < 4; ++r) {
            int grow = block_row + rowbase + quad * 4 + r;
            if (grow < N)
                Yb[(size_t)grow * NOUT + t * 16 + m] = f32_to_bf16(acc[t][r]);
        }
    }
}

// ---------------------------------------------------------------------------
// Mega-dispatch: layer-1 GEMM (fp32 x, on-the-fly bf16 convert) overlapped
// with the rank-histogram (independent work; hist backfills CU slots).
// ---------------------------------------------------------------------------
__global__ __launch_bounds__(256) void gemm1_hist(
    const float* __restrict__ x, const unsigned short* __restrict__ Wt,
    unsigned short* __restrict__ Yb, int N, int ntiles,
    const int* __restrict__ erow, int* __restrict__ cnt, int* __restrict__ rank) {
    constexpr int KP = 128 + 8;
    __shared__ unsigned short Xs[64 * KP];
    __shared__ unsigned short Ws[128 * KP];
    const int tid = threadIdx.x;

    if (blockIdx.x >= GEMM1_BLOCKS) {
        int e = (blockIdx.x - GEMM1_BLOCKS) * blockDim.x + tid;
        if (e < N_EDGES) rank[e] = atomicAdd(&cnt[(size_t)erow[e] * CNT_STRIDE], 1);
        return;
    }

    for (int idx = tid; idx < 128 * 16; idx += 256) {
        int r = idx >> 4, ch = idx & 15;
        uint4 v = *reinterpret_cast<const uint4*>(Wt + r * 128 + ch * 8);
        *reinterpret_cast<uint4*>(Ws + r * KP + ch * 8) = v;
    }

    for (int tile = blockIdx.x; tile < ntiles; tile += GEMM1_BLOCKS) {
        const int block_row = tile * 64;
        for (int idx = tid; idx < 64 * 16; idx += 256) {
            int r = idx >> 4, ch = idx & 15;
            int gr = block_row + r;
            if (gr >= N) gr = N - 1;
            const float4* xp =
                reinterpret_cast<const float4*>(x + (size_t)gr * 128 + ch * 8);
            float4 a = xp[0], b = xp[1];
            uint4 o;
            o.x = (unsigned int)f32_to_bf16(a.x) | ((unsigned int)f32_to_bf16(a.y) << 16);
            o.y = (unsigned int)f32_to_bf16(a.z) | ((unsigned int)f32_to_bf16(a.w) << 16);
            o.z = (unsigned int)f32_to_bf16(b.x) | ((unsigned int)f32_to_bf16(b.y) << 16);
            o.w = (unsigned int)f32_to_bf16(b.z) | ((unsigned int)f32_to_bf16(b.w) << 16);
            *reinterpret_cast<uint4*>(Xs + r * KP + ch * 8) = o;
        }
        __syncthreads();
        mfma_phase<128>(Xs, Ws, Yb, block_row, N);
        __syncthreads();
    }
}

// ---------------------------------------------------------------------------
// Single-dispatch scan (spin on tile-done counter; 25 blocks co-resident).
// ---------------------------------------------------------------------------
__global__ void scan_fused(const int* __restrict__ cnt, int* __restrict__ tsum,
                           int* __restrict__ done, int* __restrict__ rptr,
                           int n, int ntiles) {
    __shared__ int sums[256];
    __shared__ int off_s;
    const int t = threadIdx.x;
    const int b = blockIdx.x;
    const int base = b * SCAN_TILE + t * 8;
    int v[8], pref[8];
    int s = 0;
#pragma unroll
    for (int i = 0; i < 8; ++i) {
        v[i] = (base + i < n) ? cnt[(size_t)(base + i) * CNT_STRIDE] : 0;
        s += v[i];
    }
    sums[t] = s;
    __syncthreads();
    for (int off = 1; off < 256; off <<= 1) {
        int x = (t >= off) ? sums[t - off] : 0;
        __syncthreads();
        sums[t] += x;
        __syncthreads();
    }
    int run = sums[t] - s;
#pragma unroll
    for (int i = 0; i < 8; ++i) {
        pref[i] = run;
        run += v[i];
    }
    if (t == 255) {
        tsum[b] = run;
        __threadfence();
        atomicAdd(done, 1);
    }
    if (t == 0) {
        while (__hip_atomic_load(done, __ATOMIC_ACQUIRE, __HIP_MEMORY_SCOPE_AGENT) <
               ntiles) {
        }
        __threadfence();
        int off = 0;
        for (int i = 0; i < b; ++i) off += tsum[i];
        off_s = off;
        if (b == 0) {
            int tot = 0;
            for (int i = 0; i < ntiles; ++i) tot += tsum[i];
            rptr[n] = tot;
        }
    }
    __syncthreads();
    const int off = off_s;
#pragma unroll
    for (int i = 0; i < 8; ++i) {
        int idx = base + i;
        if (idx < n) rptr[idx] = pref[i] + off;
    }
}

// ---------------------------------------------------------------------------
// Atomic-free CSR fill: slot = rptr[row] + rank[e]; one 4B packed store.
// ---------------------------------------------------------------------------
__global__ void fill_csr(const int* __restrict__ erow, const int* __restrict__ ecol,
                         const float* __restrict__ eval, const int* __restrict__ rptr,
                         const int* __restrict__ rank,
                         unsigned int* __restrict__ cpack) {
    int e = blockIdx.x * blockDim.x + threadIdx.x;
    if (e >= N_EDGES) return;
    int slot = rptr[erow[e]] + rank[e];
    unsigned int p = (unsigned int)(ecol[e] & 0xFFFF) |
                     ((unsigned int)f32_to_bf16(eval[e]) << 16);
    cpack[slot] = p;
}

// ---------------------------------------------------------------------------
// MFMA phase, 512-thread variant (8 waves; wave w: rows (w&3)*16..+16,
// tile-columns (w>>2)*NT/2..+NT/2).
// ---------------------------------------------------------------------------
template <int NOUT>
__device__ __forceinline__ void mfma_phase512(const unsigned short* Xs,
                                              const unsigned short* Ws,
                                              unsigned short* __restrict__ Yb,
                                              int block_row, int N) {
    constexpr int KP = 128 + 8;
    constexpr int NT = NOUT / 16;
    constexpr int NTH = NT / 2;
    const int tid = threadIdx.x;
    const int wave = tid >> 6;
    const int lane = tid & 63;
    const int m = lane & 15;
    const int quad = lane >> 4;
    const int rowbase = (wave & 3) * 16;
    const int tbase = (wave >> 2) * NTH;

    f32x4 acc[NTH];
#pragma unroll
    for (int t = 0; t < NTH; ++t) acc[t] = (f32x4){0.f, 0.f, 0.f, 0.f};

#pragma unroll
    for (int kt = 0; kt < 4; ++kt) {
        bf16x8 a = *reinterpret_cast<const bf16x8*>(
            Xs + (rowbase + m) * KP + kt * 32 + quad * 8);
#pragma unroll
        for (int t = 0; t < NTH; ++t) {
            bf16x8 b = *reinterpret_cast<const bf16x8*>(
                Ws + ((tbase + t) * 16 + m) * KP + kt * 32 + quad * 8);
            acc[t] = __builtin_amdgcn_mfma_f32_16x16x32_bf16(a, b, acc[t], 0, 0, 0);
        }
    }

#pragma unroll
    for (int t = 0; t < NTH; ++t) {
#pragma unroll
        for (int r = 0; r < 4; ++r) {
            int grow = block_row + rowbase + quad * 4 + r;
            if (grow < N)
                Yb[(size_t)grow * NOUT + (tbase + t) * 16 + m] = f32_to_bf16(acc[t][r]);
        }
    }
}

// ---------------------------------------------------------------------------
// Fused aggregation + GEMM (layers 2,3), 512-thread blocks, 2 blocks/CU
// (16 waves/CU — empirically the occupancy sweet spot, r13/r15 A/B):
// Phase A: 32 groups x 16 lanes gather-aggregate 64 rows (2 rows/group,
// tiered unroll 8/4/2/1), +bias, ReLU, pack bf16 into LDS Xs.
// Phase B: mfma_phase512.
// ---------------------------------------------------------------------------
template <int NOUT>
__global__ __launch_bounds__(512, 4) void gemm_fused_agg(
    const unsigned short* __restrict__ S,
    const int* __restrict__ rptr, const unsigned int* __restrict__ cpack,
    const float* __restrict__ bias,
    const unsigned short* __restrict__ Wt,
    unsigned short* __restrict__ Yb,
    int N, int ntiles) {
    constexpr int KP = 128 + 8;
    __shared__ unsigned short Xs[64 * KP];
    __shared__ unsigned short Ws[NOUT * KP];
    const int tid = threadIdx.x;
    const int group = tid >> 4;   // 0..31
    const int f8 = tid & 15;

    for (int idx = tid; idx < NOUT * 16; idx += 512) {
        int r = idx >> 4, ch = idx & 15;
        uint4 v = *reinterpret_cast<const uint4*>(Wt + r * 128 + ch * 8);
        *reinterpret_cast<uint4*>(Ws + r * KP + ch * 8) = v;
    }

    float bv[8];
#pragma unroll
    for (int i = 0; i < 8; ++i) bv[i] = bias[f8 * 8 + i];

    for (int tile = blockIdx.x; tile < ntiles; tile += gridDim.x) {
        const int block_row = tile * 64;
#pragma unroll
        for (int r4 = 0; r4 < 2; ++r4) {
            const int row = r4 * 32 + group;
            const int node = block_row + row;
            float acc[8];
#pragma unroll
            for (int i = 0; i < 8; ++i) acc[i] = bv[i];
            if (node < N) {
                const int beg = rptr[node];
                const int end = rptr[node + 1];
                int j = beg;
                for (; j + 8 <= end; j += 8) {
                    unsigned int p[8];
                    uint4 s[8];
#pragma unroll
                    for (int u = 0; u < 8; ++u) p[u] = cpack[j + u];
#pragma unroll
                    for (int u = 0; u < 8; ++u)
                        s[u] = *reinterpret_cast<const uint4*>(
                            S + (size_t)(p[u] & 0xFFFF) * 128 + f8 * 8);
#pragma unroll
                    for (int u = 0; u < 8; ++u) {
                        const float v = bf16_to_f32((unsigned short)(p[u] >> 16));
                        const unsigned short* sp =
                            reinterpret_cast<const unsigned short*>(&s[u]);
#pragma unroll
                        for (int i = 0; i < 8; ++i)
                            acc[i] = fmaf(v, bf16_to_f32(sp[i]), acc[i]);
                    }
                }
                if (j + 4 <= end) {
                    unsigned int p[4];
                    uint4 s[4];
#pragma unroll
                    for (int u = 0; u < 4; ++u) p[u] = cpack[j + u];
#pragma unroll
                    for (int u = 0; u < 4; ++u)
                        s[u] = *reinterpret_cast<const uint4*>(
                            S + (size_t)(p[u] & 0xFFFF) * 128 + f8 * 8);
#pragma unroll
                    for (int u = 0; u < 4; ++u) {
                        const float v = bf16_to_f32((unsigned short)(p[u] >> 16));
                        const unsigned short* sp =
                            reinterpret_cast<const unsigned short*>(&s[u]);
#pragma unroll
                        for (int i = 0; i < 8; ++i)
                            acc[i] = fmaf(v, bf16_to_f32(sp[i]), acc[i]);
                    }
                    j += 4;
                }
                if (j + 2 <= end) {
                    unsigned int p[2];
                    uint4 s[2];
#pragma unroll
                    for (int u = 0; u < 2; ++u) p[u] = cpack[j + u];
#pragma unroll
                    for (int u = 0; u < 2; ++u)
                        s[u] = *reinterpret_cast<const uint4*>(
                            S + (size_t)(p[u] & 0xFFFF) * 128 + f8 * 8);
#pragma unroll
                    for (int u = 0; u < 2; ++u) {
                        const float v = bf16_to_f32((unsigned short)(p[u] >> 16));
                        const unsigned short* sp =
                            reinterpret_cast<const unsigned short*>(&s[u]);
#pragma unroll
                        for (int i = 0; i < 8; ++i)
                            acc[i] = fmaf(v, bf16_to_f32(sp[i]), acc[i]);
                    }
                    j += 2;
                }
                if (j < end) {
                    unsigned int p = cpack[j];
                    uint4 s = *reinterpret_cast<const uint4*>(
                        S + (size_t)(p & 0xFFFF) * 128 + f8 * 8);
                    const float v = bf16_to_f32((unsigned short)(p >> 16));
                    const unsigned short* sp =
                        reinterpret_cast<const unsigned short*>(&s);
#pragma unroll
                    for (int i = 0; i < 8; ++i)
                        acc[i] = fmaf(v, bf16_to_f32(sp[i]), acc[i]);
                }
            }
            uint4 o;
            o.x = (unsigned int)f32_to_bf16(fmaxf(acc[0], 0.f)) |
                  ((unsigned int)f32_to_bf16(fmaxf(acc[1], 0.f)) << 16);
            o.y = (unsigned int)f32_to_bf16(fmaxf(acc[2], 0.f)) |
                  ((unsigned int)f32_to_bf16(fmaxf(acc[3], 0.f)) << 16);
            o.z = (unsigned int)f32_to_bf16(fmaxf(acc[4], 0.f)) |
                  ((unsigned int)f32_to_bf16(fmaxf(acc[5], 0.f)) << 16);
            o.w = (unsigned int)f32_to_bf16(fmaxf(acc[6], 0.f)) |
                  ((unsigned int)f32_to_bf16(fmaxf(acc[7], 0.f)) << 16);
            *reinterpret_cast<uint4*>(Xs + row * KP + f8 * 8) = o;
        }
        __syncthreads();
        mfma_phase512<NOUT>(Xs, Ws, Yb, block_row, N);
        __syncthreads();
    }
}

// ---------------------------------------------------------------------------
// Final aggregation: bf16 source [N,64], + bias, no activation, fp32 out.
// 8 lanes/node, 8 features/lane (uint4 = 16B gathers, full-line utilization).
// Tiered unroll 8/4/2/1.
// ---------------------------------------------------------------------------
__global__ void aggregate_bf16_64(const unsigned short* __restrict__ S,
                                  const int* __restrict__ rptr,
                                  const unsigned int* __restrict__ cpack,
                                  const float* __restrict__ bias,
                                  float* __restrict__ out, int N) {
    const int node = blockIdx.x * (blockDim.x / 8) + threadIdx.x / 8;
    const int f8 = threadIdx.x & 7;
    if (node >= N) return;
    const int beg = rptr[node];
    const int end = rptr[node + 1];
    float acc[8];
#pragma unroll
    for (int i = 0; i < 8; ++i) acc[i] = bias[f8 * 8 + i];
    int j = beg;
    for (; j + 8 <= end; j += 8) {
        unsigned int p[8];
        uint4 s[8];
#pragma unroll
        for (int u = 0; u < 8; ++u) p[u] = cpack[j + u];
#pragma unroll
        for (int u = 0; u < 8; ++u)
            s[u] = *reinterpret_cast<const uint4*>(S + (size_t)(p[u] & 0xFFFF) * 64 + f8 * 8);
#pragma unroll
        for (int u = 0; u < 8; ++u) {
            const float v = bf16_to_f32((unsigned short)(p[u] >> 16));
            const unsigned short* sp = reinterpret_cast<const unsigned short*>(&s[u]);
#pragma unroll
            for (int i = 0; i < 8; ++i) acc[i] = fmaf(v, bf16_to_f32(sp[i]), acc[i]);
        }
    }
    if (j + 4 <= end) {
        unsigned int p[4];
        uint4 s[4];
#pragma unroll
        for (int u = 0; u < 4; ++u) p[u] = cpack[j + u];
#pragma unroll
        for (int u = 0; u < 4; ++u)
            s[u] = *reinterpret_cast<const uint4*>(S + (size_t)(p[u] & 0xFFFF) * 64 + f8 * 8);
#pragma unroll
        for (int u = 0; u < 4; ++u) {
            const float v = bf16_to_f32((unsigned short)(p[u] >> 16));
            const unsigned short* sp = reinterpret_cast<const unsigned short*>(&s[u]);
#pragma unroll
            for (int i = 0; i < 8; ++i) acc[i] = fmaf(v, bf16_to_f32(sp[i]), acc[i]);
        }
        j += 4;
    }
    if (j + 2 <= end) {
        unsigned int p[2];
        uint4 s[2];
#pragma unroll
        for (int u = 0; u < 2; ++u) p[u] = cpack[j + u];
#pragma unroll
        for (int u = 0; u < 2; ++u)
            s[u] = *reinterpret_cast<const uint4*>(S + (size_t)(p[u] & 0xFFFF) * 64 + f8 * 8);
#pragma unroll
        for (int u = 0; u < 2; ++u) {
            const float v = bf16_to_f32((unsigned short)(p[u] >> 16));
            const unsigned short* sp = reinterpret_cast<const unsigned short*>(&s[u]);
#pragma unroll
            for (int i = 0; i < 8; ++i) acc[i] = fmaf(v, bf16_to_f32(sp[i]), acc[i]);
        }
        j += 2;
    }
    if (j < end) {
        unsigned int p = cpack[j];
        uint4 s = *reinterpret_cast<const uint4*>(S + (size_t)(p & 0xFFFF) * 64 + f8 * 8);
        const float v = bf16_to_f32((unsigned short)(p >> 16));
        const unsigned short* sp = reinterpret_cast<const unsigned short*>(&s);
#pragma unroll
        for (int i = 0; i < 8; ++i) acc[i] = fmaf(v, bf16_to_f32(sp[i]), acc[i]);
    }
    float4 o0 = {acc[0], acc[1], acc[2], acc[3]};
    float4 o1 = {acc[4], acc[5], acc[6], acc[7]};
    float* op = out + (size_t)node * 64 + f8 * 8;
    *reinterpret_cast<float4*>(op) = o0;
    *reinterpret_cast<float4*>(op + 4) = o1;
}

extern "C" void kernel_launch(void* const* d_in, const int* in_sizes, int n_in,
                              void* d_out, int out_size, void* d_ws, size_t ws_size,
                              hipStream_t stream) {
    const float* x    = (const float*)d_in[0];
    const int*   erow = (const int*)d_in[1];
    const int*   ecol = (const int*)d_in[2];
    const float* eval = (const float*)d_in[3];
    const float* W1   = (const float*)d_in[4];
    const float* b1   = (const float*)d_in[5];
    const float* W2   = (const float*)d_in[6];
    const float* b2   = (const float*)d_in[7];
    const float* W3   = (const float*)d_in[8];
    const float* b3   = (const float*)d_in[9];
    float* out = (float*)d_out;

    const size_t nf = (size_t)N_NODES * 128;
    unsigned short* SA  = (unsigned short*)d_ws;     // support A (A1, then A3)
    unsigned short* SB  = SA + nf;                   // support B (A2)
    unsigned short* Wt1 = SB + nf;
    unsigned short* Wt2 = Wt1 + 128 * 128;
    unsigned short* Wt3 = Wt2 + 128 * 128;
    int*   cnt    = (int*)(Wt3 + 64 * 128);              // N_NODES * CNT_STRIDE
    int*   rank   = cnt + (size_t)N_NODES * CNT_STRIDE;  // N_EDGES
    int*   rptr   = rank + N_EDGES;                      // N_NODES + 1
    unsigned int* cpack = (unsigned int*)(rptr + N_NODES + 1);  // N_EDGES
    int*   stsum  = (int*)(cpack + N_EDGES);             // tiles
    int*   done   = cnt + 1;  // unused cnt slot

    const int blk = 256;
    const int ntiles_g = (N_NODES + 63) / 64;
    const int agg_grid = (int)(((long long)N_NODES * 8 + blk - 1) / blk);
    const int ntiles = (N_NODES + SCAN_TILE - 1) / SCAN_TILE;

    // ---- 1. prep: zero cnt + W transposes (one dispatch)
    {
        long long total = (long long)CNT4 + W128 + W128 + W64;
        prep<<<(int)((total + blk - 1) / blk), blk, 0, stream>>>(
            cnt, W1, W2, W3, Wt1, Wt2, Wt3);
    }

    // ---- 2. layer-1 GEMM overlapped with rank-histogram
    gemm1_hist<<<GEMM1_BLOCKS + HIST_BLOCKS, 256, 0, stream>>>(
        x, Wt1, SA, N_NODES, ntiles_g, erow, cnt, rank);

    // ---- 3. scan -> rptr
    scan_fused<<<ntiles, 256, 0, stream>>>(cnt, stsum, done, rptr, N_NODES, ntiles);

    // ---- 4. atomic-free CSR fill
    fill_csr<<<HIST_BLOCKS, blk, 0, stream>>>(erow, ecol, eval, rptr, rank, cpack);

    // ---- 5. Layer 2: fused agg(A1)+ReLU+b1 -> GEMM W2 -> A2
    gemm_fused_agg<128><<<FUSED_BLOCKS, 512, 0, stream>>>(
        SA, rptr, cpack, b1, Wt2, SB, N_NODES, ntiles_g);

    // ---- 6. Layer 3: fused agg(A2)+ReLU+b2 -> GEMM W3 -> A3 (64-wide)
    gemm_fused_agg<64><<<FUSED_BLOCKS, 512, 0, stream>>>(
        SB, rptr, cpack, b2, Wt3, SA, N_NODES, ntiles_g);

    // ---- 7. Final aggregation: A3 + b3 -> out (fp32)
    aggregate_bf16_64<<<agg_grid, blk, 0, stream>>>(SA, rptr, cpack, b3, out, N_NODES);
}